// Round 2
// baseline (193.329 us; speedup 1.0000x reference)
//
#include <hip/hip_runtime.h>
#include <hip/hip_bf16.h>

// EdgeWeightFromDistance: out[e] = relu(relu([x[src], y[dst], dist] @ W1 + b1) @ W2 + b2)
// E = 1e6, NODE_DIM = 64, HIDDEN = 128.
// Strategy: bf16 MFMA (16x16x32) for the K=128 part (x|y), dist*W1[128,:] + b1 in fp32,
// second layer fp32 VALU + quad shuffle reduction. A-fragments gathered straight from
// global (8 consecutive floats per lane), B (W1^T) held in registers per wave.
// R2: grid 512 -> 1024 (4 blocks/CU, the VGPR/LDS-allowed max; was latency-bound at 2).

constexpr int NDIM  = 64;
constexpr int HID   = 128;
constexpr int KPAD  = 136;   // LDS K stride (bf16 elems); 272 B row: 16B-aligned b128 reads

typedef __attribute__((ext_vector_type(8))) short  short8;
typedef __attribute__((ext_vector_type(4))) int    int4v;
typedef __attribute__((ext_vector_type(4))) float  floatx4;

__device__ __forceinline__ short f2bf(float f) {
    union { __hip_bfloat16 h; short s; } cv;
    cv.h = __float2bfloat16(f);
    return cv.s;
}

__device__ __forceinline__ int pack2(float a, float b) {
    union { __hip_bfloat162 h; int u; } cv;
    cv.h = __float22bfloat162_rn(float2{a, b});
    return cv.u;
}

__global__ __launch_bounds__(256) void edge_mlp_kernel(
    const float* __restrict__ x, const float* __restrict__ y,
    const int*  __restrict__ ei, const float* __restrict__ px,
    const float* __restrict__ py, const float* __restrict__ W1,
    const float* __restrict__ b1, const float* __restrict__ W2,
    const float* __restrict__ b2, float* __restrict__ out, int E)
{
    __shared__ __align__(16) short Wt[HID * KPAD];   // W1^T [n][k] in bf16

    const int tid = threadIdx.x;

    // ---- stage W1[0:128][0:128] transposed into LDS (one-time per block) ----
    // i = k*128 + n ; coalesced global read, batched 8 loads for latency.
    for (int base = 0; base < HID * HID; base += 256 * 8) {
        float f[8];
#pragma unroll
        for (int u = 0; u < 8; ++u) f[u] = W1[base + u * 256 + tid];
#pragma unroll
        for (int u = 0; u < 8; ++u) {
            int i = base + u * 256 + tid;
            Wt[(i & 127) * KPAD + (i >> 7)] = f2bf(f[u]);
        }
    }
    __syncthreads();

    const int lane = tid & 63;
    const int wave = tid >> 6;
    const int quad = lane >> 4;
    const int lm   = lane & 15;   // A-frag row m; C/D col n (within tile)

    // ---- hoist all B fragments into registers: 8 n-tiles x 4 k-steps ----
    // B[k][n] fragment: n = ntile*16 + lm, k = kstep*32 + quad*8 + j (j=0..7)
    short8 bfrag[8][4];
#pragma unroll
    for (int t = 0; t < 8; ++t) {
        const int n = t * 16 + lm;
#pragma unroll
        for (int s = 0; s < 4; ++s) {
            const int k0 = s * 32 + quad * 8;
            bfrag[t][s] = *reinterpret_cast<const short8*>(&Wt[n * KPAD + k0]);
        }
    }

    // epilogue constants for this lane's n columns (n = t*16 + lm)
    float b1v[8], w2v[8], w1rv[8];
#pragma unroll
    for (int t = 0; t < 8; ++t) {
        const int n = t * 16 + lm;
        b1v[t]  = b1[n];
        w2v[t]  = W2[n];
        w1rv[t] = W1[128 * HID + n];   // last row of W1: the dist coefficient
    }
    const float b2s = b2[0];

    const int* __restrict__ srcp = ei;
    const int* __restrict__ dstp = ei + E;

    const int ntile_cnt = E / 64;   // 64 edges per block-iteration (16 per wave)
    for (int tile = blockIdx.x; tile < ntile_cnt; tile += gridDim.x) {
        const int m_base = tile * 64 + wave * 16;
        int m = m_base + lm;
        if (m >= E) m = E - 1;               // safety clamp (E % 64 == 0 here)
        const int src = srcp[m];
        const int dst = dstp[m];

        // per-edge distance (every lane computes for m = m_base + lm; quads duplicate)
        const float dx = px[src * 3 + 0] - py[dst * 3 + 0];
        const float dy = px[src * 3 + 1] - py[dst * 3 + 1];
        const float dz = px[src * 3 + 2] - py[dst * 3 + 2];
        const float dist = sqrtf(dx * dx + dy * dy + dz * dz);

        // ---- A fragments: row m, k = s*32 + quad*8 + j ; straight from global ----
        short8 afrag[4];
#pragma unroll
        for (int s = 0; s < 4; ++s) {
            const int kk = s * 32 + quad * 8;
            const float* rp = (s < 2) ? (x + src * NDIM + kk)
                                      : (y + dst * NDIM + (kk - 64));
            const floatx4 f0 = *reinterpret_cast<const floatx4*>(rp);
            const floatx4 f1 = *reinterpret_cast<const floatx4*>(rp + 4);
            union { int4v i; short8 s8; } cv;
            cv.i.x = pack2(f0.x, f0.y);
            cv.i.y = pack2(f0.z, f0.w);
            cv.i.z = pack2(f1.x, f1.y);
            cv.i.w = pack2(f1.z, f1.w);
            afrag[s] = cv.s8;
        }

        // ---- MFMA: h[16 edges][128 hidden], fp32 accumulate ----
        floatx4 acc[8];
#pragma unroll
        for (int t = 0; t < 8; ++t) acc[t] = floatx4{0.f, 0.f, 0.f, 0.f};
#pragma unroll
        for (int s = 0; s < 4; ++s) {
#pragma unroll
            for (int t = 0; t < 8; ++t) {
                acc[t] = __builtin_amdgcn_mfma_f32_16x16x32_bf16(
                    afrag[s], bfrag[t][s], acc[t], 0, 0, 0);
            }
        }

        // ---- epilogue: + dist*W1[128,n] + b1, ReLU, dot W2, reduce, +b2, ReLU ----
        // C/D layout: col n = lm (+16t), row m = quad*4 + reg
        const float dm0 = __shfl(dist, quad * 4 + 0, 64);
        const float dm1 = __shfl(dist, quad * 4 + 1, 64);
        const float dm2 = __shfl(dist, quad * 4 + 2, 64);
        const float dm3 = __shfl(dist, quad * 4 + 3, 64);

        float p0 = 0.f, p1 = 0.f, p2 = 0.f, p3 = 0.f;
#pragma unroll
        for (int t = 0; t < 8; ++t) {
            float h;
            h = acc[t][0] + dm0 * w1rv[t] + b1v[t]; h = fmaxf(h, 0.f); p0 += h * w2v[t];
            h = acc[t][1] + dm1 * w1rv[t] + b1v[t]; h = fmaxf(h, 0.f); p1 += h * w2v[t];
            h = acc[t][2] + dm2 * w1rv[t] + b1v[t]; h = fmaxf(h, 0.f); p2 += h * w2v[t];
            h = acc[t][3] + dm3 * w1rv[t] + b1v[t]; h = fmaxf(h, 0.f); p3 += h * w2v[t];
        }
        // sum over the 16 lanes of this quad (covers all 128 n columns)
#pragma unroll
        for (int off = 1; off < 16; off <<= 1) {
            p0 += __shfl_xor(p0, off, 64);
            p1 += __shfl_xor(p1, off, 64);
            p2 += __shfl_xor(p2, off, 64);
            p3 += __shfl_xor(p3, off, 64);
        }
        if (lm < 4) {
            const float v = (lm == 0) ? p0 : (lm == 1) ? p1 : (lm == 2) ? p2 : p3;
            const int e = m_base + quad * 4 + lm;
            if (e < E) out[e] = fmaxf(v + b2s, 0.f);
        }
    }
}

extern "C" void kernel_launch(void* const* d_in, const int* in_sizes, int n_in,
                              void* d_out, int out_size, void* d_ws, size_t ws_size,
                              hipStream_t stream)
{
    const float* x  = (const float*)d_in[0];
    const float* y  = (const float*)d_in[1];
    const int*   ei = (const int*)  d_in[2];
    const float* px = (const float*)d_in[3];
    const float* py = (const float*)d_in[4];
    const float* W1 = (const float*)d_in[5];
    const float* b1 = (const float*)d_in[6];
    const float* W2 = (const float*)d_in[7];
    const float* b2 = (const float*)d_in[8];
    float* out = (float*)d_out;
    const int E = in_sizes[2] / 2;

    // 1024 blocks = 4 blocks/CU (the VGPR/LDS-allowed residency max).
    edge_mlp_kernel<<<dim3(1024), dim3(256), 0, stream>>>(
        x, y, ei, px, py, W1, b1, W2, b2, out, E);
}

// Round 3
// 192.369 us; speedup vs baseline: 1.0050x; 1.0050x over previous
//
#include <hip/hip_runtime.h>
#include <hip/hip_bf16.h>

// EdgeWeightFromDistance: out[e] = relu(relu([x[src], y[dst], dist] @ W1 + b1) @ W2 + b2)
// E = 1e6, NODE_DIM = 64, HIDDEN = 128.
// R3: occupancy was register-limited (bfrag[8][4] = 128 unified regs -> 2 waves/SIMD).
//  - B-fragments now read from LDS per iteration (asm guard blocks LICM re-hoist).
//  - M=32 edges/wave (two m-tiles share every B read).
//  - dist*W1[128,:] + b1 folded into a 5th MFMA k-step (Wt k=128 -> w1r, k=129 -> b1;
//    A = {dist, 1.0} on quad 0, zeros elsewhere) -- removes broadcasts + 64 VALU/iter.
//  - __launch_bounds__(256,3), grid 768 = 3 blocks/CU (12 waves/CU target).

constexpr int NDIM  = 64;
constexpr int HID   = 128;
constexpr int KPAD  = 136;   // bf16 elems per Wt row: 128 data + w1r + b1 + 6 zeros; 272 B (16B-aligned)

typedef __attribute__((ext_vector_type(8))) short  short8;
typedef __attribute__((ext_vector_type(4))) int    int4v;
typedef __attribute__((ext_vector_type(4))) float  floatx4;

__device__ __forceinline__ short f2bf(float f) {
    union { __hip_bfloat16 h; short s; } cv;
    cv.h = __float2bfloat16(f);
    return cv.s;
}

__device__ __forceinline__ int pack2(float a, float b) {
    union { __hip_bfloat162 h; int u; } cv;
    cv.h = __float22bfloat162_rn(float2{a, b});
    return cv.u;
}

__device__ __forceinline__ short8 make_afrag(const float* rp) {
    const floatx4 f0 = *reinterpret_cast<const floatx4*>(rp);
    const floatx4 f1 = *reinterpret_cast<const floatx4*>(rp + 4);
    union { int4v i; short8 s8; } cv;
    cv.i.x = pack2(f0.x, f0.y);
    cv.i.y = pack2(f0.z, f0.w);
    cv.i.z = pack2(f1.x, f1.y);
    cv.i.w = pack2(f1.z, f1.w);
    return cv.s8;
}

__global__ __launch_bounds__(256, 3) void edge_mlp_kernel(
    const float* __restrict__ x, const float* __restrict__ y,
    const int*  __restrict__ ei, const float* __restrict__ px,
    const float* __restrict__ py, const float* __restrict__ W1,
    const float* __restrict__ b1, const float* __restrict__ W2,
    const float* __restrict__ b2, float* __restrict__ out, int E)
{
    __shared__ __align__(16) short Wt[HID * KPAD];   // W1^T [n][k] in bf16 (+ fold rows)

    const int tid = threadIdx.x;

    // ---- stage W1[0:128][0:128] transposed into LDS ----
    for (int base = 0; base < HID * HID; base += 256 * 8) {
        float f[8];
#pragma unroll
        for (int u = 0; u < 8; ++u) f[u] = W1[base + u * 256 + tid];
#pragma unroll
        for (int u = 0; u < 8; ++u) {
            int i = base + u * 256 + tid;
            Wt[(i & 127) * KPAD + (i >> 7)] = f2bf(f[u]);
        }
    }
    // fold rows: k=128 -> w1r (dist coeff), k=129 -> b1, k=130..135 -> 0
    if (tid < HID) {
        const int n = tid;
        Wt[n * KPAD + 128] = f2bf(W1[128 * HID + n]);
        Wt[n * KPAD + 129] = f2bf(b1[n]);
#pragma unroll
        for (int j = 130; j < 136; ++j) Wt[n * KPAD + j] = 0;
    }
    __syncthreads();

    const int lane = tid & 63;
    const int wave = tid >> 6;
    const int quad = lane >> 4;
    const int lm   = lane & 15;   // A-frag row m; B-frag/C-D col n (within tile)

    float w2v[8];
#pragma unroll
    for (int t = 0; t < 8; ++t) w2v[t] = W2[t * 16 + lm];
    const float b2s = b2[0];

    const int* __restrict__ srcp = ei;
    const int* __restrict__ dstp = ei + E;

    const int sel5 = (quad == 0) ? 128 : 0;   // fold-step k-offset (q>0 lanes: A=0, B=any finite)

    const int ntiles = (E + 127) / 128;       // 128 edges per block-iter, 32 per wave
    for (int tile = blockIdx.x; tile < ntiles; tile += gridDim.x) {
        const int mb = tile * 128 + wave * 32;
        int m0 = mb + lm;       if (m0 >= E) m0 = E - 1;
        int m1 = mb + 16 + lm;  if (m1 >= E) m1 = E - 1;
        const int src0 = srcp[m0], dst0 = dstp[m0];
        const int src1 = srcp[m1], dst1 = dstp[m1];

        const float dx0 = px[src0 * 3 + 0] - py[dst0 * 3 + 0];
        const float dy0 = px[src0 * 3 + 1] - py[dst0 * 3 + 1];
        const float dz0 = px[src0 * 3 + 2] - py[dst0 * 3 + 2];
        const float dist0 = sqrtf(dx0 * dx0 + dy0 * dy0 + dz0 * dz0);
        const float dx1 = px[src1 * 3 + 0] - py[dst1 * 3 + 0];
        const float dy1 = px[src1 * 3 + 1] - py[dst1 * 3 + 1];
        const float dz1 = px[src1 * 3 + 2] - py[dst1 * 3 + 2];
        const float dist1 = sqrtf(dx1 * dx1 + dy1 * dy1 + dz1 * dz1);

        // ---- A fragments: row m, k = s*32 + quad*8 + j ; straight from global ----
        short8 fa[4], fb[4];
#pragma unroll
        for (int s = 0; s < 4; ++s) {
            const int kk = s * 32 + quad * 8;
            fa[s] = make_afrag((s < 2) ? (x + src0 * NDIM + kk) : (y + dst0 * NDIM + (kk - 64)));
            fb[s] = make_afrag((s < 2) ? (x + src1 * NDIM + kk) : (y + dst1 * NDIM + (kk - 64)));
        }
        // fold-step A: k=128 -> dist, k=129 -> 1.0 (quad 0 only; others zero)
        short8 fa4, fb4;
        {
            union { int4v i; short8 s8; } ca, cb;
            const int d0 = (quad == 0) ? pack2(dist0, 1.0f) : 0;
            const int d1 = (quad == 0) ? pack2(dist1, 1.0f) : 0;
            ca.i = int4v{d0, 0, 0, 0};
            cb.i = int4v{d1, 0, 0, 0};
            fa4 = ca.s8; fb4 = cb.s8;
        }

        floatx4 accA[8], accB[8];
#pragma unroll
        for (int t = 0; t < 8; ++t) {
            accA[t] = floatx4{0.f, 0.f, 0.f, 0.f};
            accB[t] = floatx4{0.f, 0.f, 0.f, 0.f};
        }

        // B-fragments from LDS each iteration; zoff guard defeats LICM (keeps regs low).
        int zoff = 0;
        asm volatile("" : "+v"(zoff));
        const short* wr  = Wt + zoff + lm * KPAD + quad * 8;
        const short* wr5 = Wt + zoff + lm * KPAD + sel5;

#pragma unroll
        for (int t = 0; t < 8; ++t) {
            const short* base = wr + t * (16 * KPAD);
            const short8 bg0 = *reinterpret_cast<const short8*>(base);
            const short8 bg1 = *reinterpret_cast<const short8*>(base + 32);
            const short8 bg2 = *reinterpret_cast<const short8*>(base + 64);
            const short8 bg3 = *reinterpret_cast<const short8*>(base + 96);
            const short8 bg4 = *reinterpret_cast<const short8*>(wr5 + t * (16 * KPAD));
            accA[t] = __builtin_amdgcn_mfma_f32_16x16x32_bf16(fa[0], bg0, accA[t], 0, 0, 0);
            accB[t] = __builtin_amdgcn_mfma_f32_16x16x32_bf16(fb[0], bg0, accB[t], 0, 0, 0);
            accA[t] = __builtin_amdgcn_mfma_f32_16x16x32_bf16(fa[1], bg1, accA[t], 0, 0, 0);
            accB[t] = __builtin_amdgcn_mfma_f32_16x16x32_bf16(fb[1], bg1, accB[t], 0, 0, 0);
            accA[t] = __builtin_amdgcn_mfma_f32_16x16x32_bf16(fa[2], bg2, accA[t], 0, 0, 0);
            accB[t] = __builtin_amdgcn_mfma_f32_16x16x32_bf16(fb[2], bg2, accB[t], 0, 0, 0);
            accA[t] = __builtin_amdgcn_mfma_f32_16x16x32_bf16(fa[3], bg3, accA[t], 0, 0, 0);
            accB[t] = __builtin_amdgcn_mfma_f32_16x16x32_bf16(fb[3], bg3, accB[t], 0, 0, 0);
            accA[t] = __builtin_amdgcn_mfma_f32_16x16x32_bf16(fa4,  bg4, accA[t], 0, 0, 0);
            accB[t] = __builtin_amdgcn_mfma_f32_16x16x32_bf16(fb4,  bg4, accB[t], 0, 0, 0);
        }

        // ---- epilogue: relu, dot W2 (over n), quad-group reduce, +b2, relu ----
        // C/D layout: col n = lm + 16t, row m = quad*4 + reg
        float p0 = 0.f, p1 = 0.f, p2 = 0.f, p3 = 0.f;
        float q0 = 0.f, q1 = 0.f, q2 = 0.f, q3 = 0.f;
#pragma unroll
        for (int t = 0; t < 8; ++t) {
            p0 += fmaxf(accA[t][0], 0.f) * w2v[t];
            p1 += fmaxf(accA[t][1], 0.f) * w2v[t];
            p2 += fmaxf(accA[t][2], 0.f) * w2v[t];
            p3 += fmaxf(accA[t][3], 0.f) * w2v[t];
            q0 += fmaxf(accB[t][0], 0.f) * w2v[t];
            q1 += fmaxf(accB[t][1], 0.f) * w2v[t];
            q2 += fmaxf(accB[t][2], 0.f) * w2v[t];
            q3 += fmaxf(accB[t][3], 0.f) * w2v[t];
        }
#pragma unroll
        for (int off = 1; off < 16; off <<= 1) {
            p0 += __shfl_xor(p0, off, 64);
            p1 += __shfl_xor(p1, off, 64);
            p2 += __shfl_xor(p2, off, 64);
            p3 += __shfl_xor(p3, off, 64);
            q0 += __shfl_xor(q0, off, 64);
            q1 += __shfl_xor(q1, off, 64);
            q2 += __shfl_xor(q2, off, 64);
            q3 += __shfl_xor(q3, off, 64);
        }
        if (lm < 4) {
            const float vA = (lm == 0) ? p0 : (lm == 1) ? p1 : (lm == 2) ? p2 : p3;
            const float vB = (lm == 0) ? q0 : (lm == 1) ? q1 : (lm == 2) ? q2 : q3;
            const int eA = mb + quad * 4 + lm;
            const int eB = mb + 16 + quad * 4 + lm;
            if (eA < E) out[eA] = fmaxf(vA + b2s, 0.f);
            if (eB < E) out[eB] = fmaxf(vB + b2s, 0.f);
        }
    }
}

extern "C" void kernel_launch(void* const* d_in, const int* in_sizes, int n_in,
                              void* d_out, int out_size, void* d_ws, size_t ws_size,
                              hipStream_t stream)
{
    const float* x  = (const float*)d_in[0];
    const float* y  = (const float*)d_in[1];
    const int*   ei = (const int*)  d_in[2];
    const float* px = (const float*)d_in[3];
    const float* py = (const float*)d_in[4];
    const float* W1 = (const float*)d_in[5];
    const float* b1 = (const float*)d_in[6];
    const float* W2 = (const float*)d_in[7];
    const float* b2 = (const float*)d_in[8];
    float* out = (float*)d_out;
    const int E = in_sizes[2] / 2;

    // 768 blocks = 3 blocks/CU at __launch_bounds__(256,3) (register-allowed residency).
    edge_mlp_kernel<<<dim3(768), dim3(256), 0, stream>>>(
        x, y, ei, px, py, W1, b1, W2, b2, out, E);
}

// Round 4
// 162.561 us; speedup vs baseline: 1.1893x; 1.1834x over previous
//
#include <hip/hip_runtime.h>
#include <hip/hip_bf16.h>

// EdgeWeightFromDistance: out[e] = relu(relu([x[src], y[dst], dist] @ W1 + b1) @ W2 + b2)
// E = 1e6, NODE_DIM = 64, HIDDEN = 128.
// R4: three configs all pinned at ~105 µs with FETCH_SIZE ~313 MB @ ~3 TB/s beyond-L2
//     -> gather-byte wall, not CU-side. Pre-convert x,y to bf16 in d_ws (numerically
//     identical to the in-loop pack we already did) => gather bytes halve (512->256 MB
//     logical), cacheline touches/edge halve, in-loop pack VALU deleted.
//     Fallback to fp32-gather path if ws_size < 25.6 MB.

constexpr int NDIM  = 64;
constexpr int HID   = 128;
constexpr int KPAD  = 136;   // bf16 elems per Wt row: 128 data + w1r + b1 + 6 zeros; 272 B

typedef __attribute__((ext_vector_type(8))) short  short8;
typedef __attribute__((ext_vector_type(4))) int    int4v;
typedef __attribute__((ext_vector_type(4))) float  floatx4;

__device__ __forceinline__ short f2bf(float f) {
    union { __hip_bfloat16 h; short s; } cv;
    cv.h = __float2bfloat16(f);
    return cv.s;
}

__device__ __forceinline__ int pack2(float a, float b) {
    union { __hip_bfloat162 h; int u; } cv;
    cv.h = __float22bfloat162_rn(float2{a, b});
    return cv.u;
}

__device__ __forceinline__ short8 make_afrag_f32(const float* rp) {
    const floatx4 f0 = *reinterpret_cast<const floatx4*>(rp);
    const floatx4 f1 = *reinterpret_cast<const floatx4*>(rp + 4);
    union { int4v i; short8 s8; } cv;
    cv.i.x = pack2(f0.x, f0.y);
    cv.i.y = pack2(f0.z, f0.w);
    cv.i.z = pack2(f1.x, f1.y);
    cv.i.w = pack2(f1.z, f1.w);
    return cv.s8;
}

// ---- streaming fp32 -> bf16 convert of x and y into workspace ----
__global__ __launch_bounds__(256) void cvt_kernel(
    const float* __restrict__ xin, const float* __restrict__ yin,
    short* __restrict__ xb, short* __restrict__ yb, int nfl)  // nfl = elems per array
{
    const int stride = gridDim.x * blockDim.x;
    const int n8 = nfl >> 3;
    for (int i = blockIdx.x * blockDim.x + threadIdx.x; i < n8; i += stride) {
        {
            const floatx4 f0 = *reinterpret_cast<const floatx4*>(xin + i * 8);
            const floatx4 f1 = *reinterpret_cast<const floatx4*>(xin + i * 8 + 4);
            union { int4v v; short8 s; } c;
            c.v.x = pack2(f0.x, f0.y); c.v.y = pack2(f0.z, f0.w);
            c.v.z = pack2(f1.x, f1.y); c.v.w = pack2(f1.z, f1.w);
            *reinterpret_cast<short8*>(xb + i * 8) = c.s;
        }
        {
            const floatx4 f0 = *reinterpret_cast<const floatx4*>(yin + i * 8);
            const floatx4 f1 = *reinterpret_cast<const floatx4*>(yin + i * 8 + 4);
            union { int4v v; short8 s; } c;
            c.v.x = pack2(f0.x, f0.y); c.v.y = pack2(f0.z, f0.w);
            c.v.z = pack2(f1.x, f1.y); c.v.w = pack2(f1.z, f1.w);
            *reinterpret_cast<short8*>(yb + i * 8) = c.s;
        }
    }
}

template <bool BF16GATHER>
__global__ __launch_bounds__(256, 3) void edge_mlp_kernel(
    const float* __restrict__ x, const float* __restrict__ y,
    const short* __restrict__ xb, const short* __restrict__ yb,
    const int*  __restrict__ ei, const float* __restrict__ px,
    const float* __restrict__ py, const float* __restrict__ W1,
    const float* __restrict__ b1, const float* __restrict__ W2,
    const float* __restrict__ b2, float* __restrict__ out, int E)
{
    __shared__ __align__(16) short Wt[HID * KPAD];   // W1^T [n][k] in bf16 (+ fold rows)

    const int tid = threadIdx.x;

    // ---- stage W1[0:128][0:128] transposed into LDS ----
    for (int base = 0; base < HID * HID; base += 256 * 8) {
        float f[8];
#pragma unroll
        for (int u = 0; u < 8; ++u) f[u] = W1[base + u * 256 + tid];
#pragma unroll
        for (int u = 0; u < 8; ++u) {
            int i = base + u * 256 + tid;
            Wt[(i & 127) * KPAD + (i >> 7)] = f2bf(f[u]);
        }
    }
    // fold rows: k=128 -> w1r (dist coeff), k=129 -> b1, k=130..135 -> 0
    if (tid < HID) {
        const int n = tid;
        Wt[n * KPAD + 128] = f2bf(W1[128 * HID + n]);
        Wt[n * KPAD + 129] = f2bf(b1[n]);
#pragma unroll
        for (int j = 130; j < 136; ++j) Wt[n * KPAD + j] = 0;
    }
    __syncthreads();

    const int lane = tid & 63;
    const int wave = tid >> 6;
    const int quad = lane >> 4;
    const int lm   = lane & 15;   // A-frag row m; B-frag/C-D col n (within tile)

    float w2v[8];
#pragma unroll
    for (int t = 0; t < 8; ++t) w2v[t] = W2[t * 16 + lm];
    const float b2s = b2[0];

    const int* __restrict__ srcp = ei;
    const int* __restrict__ dstp = ei + E;

    const int sel5 = (quad == 0) ? 128 : 0;   // fold-step k-offset

    const int ntiles = (E + 127) / 128;       // 128 edges per block-iter, 32 per wave
    for (int tile = blockIdx.x; tile < ntiles; tile += gridDim.x) {
        const int mb = tile * 128 + wave * 32;
        int m0 = mb + lm;       if (m0 >= E) m0 = E - 1;
        int m1 = mb + 16 + lm;  if (m1 >= E) m1 = E - 1;
        const int src0 = srcp[m0], dst0 = dstp[m0];
        const int src1 = srcp[m1], dst1 = dstp[m1];

        const float dx0 = px[src0 * 3 + 0] - py[dst0 * 3 + 0];
        const float dy0 = px[src0 * 3 + 1] - py[dst0 * 3 + 1];
        const float dz0 = px[src0 * 3 + 2] - py[dst0 * 3 + 2];
        const float dist0 = sqrtf(dx0 * dx0 + dy0 * dy0 + dz0 * dz0);
        const float dx1 = px[src1 * 3 + 0] - py[dst1 * 3 + 0];
        const float dy1 = px[src1 * 3 + 1] - py[dst1 * 3 + 1];
        const float dz1 = px[src1 * 3 + 2] - py[dst1 * 3 + 2];
        const float dist1 = sqrtf(dx1 * dx1 + dy1 * dy1 + dz1 * dz1);

        // ---- A fragments: row m, k = s*32 + quad*8 + j ----
        short8 fa[4], fb[4];
#pragma unroll
        for (int s = 0; s < 4; ++s) {
            const int kk = s * 32 + quad * 8;
            if (BF16GATHER) {
                const short* pa = (s < 2) ? (xb + src0 * NDIM + kk)
                                          : (yb + dst0 * NDIM + (kk - 64));
                const short* pb = (s < 2) ? (xb + src1 * NDIM + kk)
                                          : (yb + dst1 * NDIM + (kk - 64));
                fa[s] = *reinterpret_cast<const short8*>(pa);
                fb[s] = *reinterpret_cast<const short8*>(pb);
            } else {
                fa[s] = make_afrag_f32((s < 2) ? (x + src0 * NDIM + kk)
                                               : (y + dst0 * NDIM + (kk - 64)));
                fb[s] = make_afrag_f32((s < 2) ? (x + src1 * NDIM + kk)
                                               : (y + dst1 * NDIM + (kk - 64)));
            }
        }
        // fold-step A: k=128 -> dist, k=129 -> 1.0 (quad 0 only; others zero)
        short8 fa4, fb4;
        {
            union { int4v i; short8 s8; } ca, cb;
            const int d0 = (quad == 0) ? pack2(dist0, 1.0f) : 0;
            const int d1 = (quad == 0) ? pack2(dist1, 1.0f) : 0;
            ca.i = int4v{d0, 0, 0, 0};
            cb.i = int4v{d1, 0, 0, 0};
            fa4 = ca.s8; fb4 = cb.s8;
        }

        floatx4 accA[8], accB[8];
#pragma unroll
        for (int t = 0; t < 8; ++t) {
            accA[t] = floatx4{0.f, 0.f, 0.f, 0.f};
            accB[t] = floatx4{0.f, 0.f, 0.f, 0.f};
        }

        // B-fragments from LDS each iteration; zoff guard defeats LICM (keeps regs low).
        int zoff = 0;
        asm volatile("" : "+v"(zoff));
        const short* wr  = Wt + zoff + lm * KPAD + quad * 8;
        const short* wr5 = Wt + zoff + lm * KPAD + sel5;

#pragma unroll
        for (int t = 0; t < 8; ++t) {
            const short* base = wr + t * (16 * KPAD);
            const short8 bg0 = *reinterpret_cast<const short8*>(base);
            const short8 bg1 = *reinterpret_cast<const short8*>(base + 32);
            const short8 bg2 = *reinterpret_cast<const short8*>(base + 64);
            const short8 bg3 = *reinterpret_cast<const short8*>(base + 96);
            const short8 bg4 = *reinterpret_cast<const short8*>(wr5 + t * (16 * KPAD));
            accA[t] = __builtin_amdgcn_mfma_f32_16x16x32_bf16(fa[0], bg0, accA[t], 0, 0, 0);
            accB[t] = __builtin_amdgcn_mfma_f32_16x16x32_bf16(fb[0], bg0, accB[t], 0, 0, 0);
            accA[t] = __builtin_amdgcn_mfma_f32_16x16x32_bf16(fa[1], bg1, accA[t], 0, 0, 0);
            accB[t] = __builtin_amdgcn_mfma_f32_16x16x32_bf16(fb[1], bg1, accB[t], 0, 0, 0);
            accA[t] = __builtin_amdgcn_mfma_f32_16x16x32_bf16(fa[2], bg2, accA[t], 0, 0, 0);
            accB[t] = __builtin_amdgcn_mfma_f32_16x16x32_bf16(fb[2], bg2, accB[t], 0, 0, 0);
            accA[t] = __builtin_amdgcn_mfma_f32_16x16x32_bf16(fa[3], bg3, accA[t], 0, 0, 0);
            accB[t] = __builtin_amdgcn_mfma_f32_16x16x32_bf16(fb[3], bg3, accB[t], 0, 0, 0);
            accA[t] = __builtin_amdgcn_mfma_f32_16x16x32_bf16(fa4,  bg4, accA[t], 0, 0, 0);
            accB[t] = __builtin_amdgcn_mfma_f32_16x16x32_bf16(fb4,  bg4, accB[t], 0, 0, 0);
        }

        // ---- epilogue: relu, dot W2 (over n), quad-group reduce, +b2, relu ----
        // C/D layout: col n = lm + 16t, row m = quad*4 + reg
        float p0 = 0.f, p1 = 0.f, p2 = 0.f, p3 = 0.f;
        float q0 = 0.f, q1 = 0.f, q2 = 0.f, q3 = 0.f;
#pragma unroll
        for (int t = 0; t < 8; ++t) {
            p0 += fmaxf(accA[t][0], 0.f) * w2v[t];
            p1 += fmaxf(accA[t][1], 0.f) * w2v[t];
            p2 += fmaxf(accA[t][2], 0.f) * w2v[t];
            p3 += fmaxf(accA[t][3], 0.f) * w2v[t];
            q0 += fmaxf(accB[t][0], 0.f) * w2v[t];
            q1 += fmaxf(accB[t][1], 0.f) * w2v[t];
            q2 += fmaxf(accB[t][2], 0.f) * w2v[t];
            q3 += fmaxf(accB[t][3], 0.f) * w2v[t];
        }
#pragma unroll
        for (int off = 1; off < 16; off <<= 1) {
            p0 += __shfl_xor(p0, off, 64);
            p1 += __shfl_xor(p1, off, 64);
            p2 += __shfl_xor(p2, off, 64);
            p3 += __shfl_xor(p3, off, 64);
            q0 += __shfl_xor(q0, off, 64);
            q1 += __shfl_xor(q1, off, 64);
            q2 += __shfl_xor(q2, off, 64);
            q3 += __shfl_xor(q3, off, 64);
        }
        if (lm < 4) {
            const float vA = (lm == 0) ? p0 : (lm == 1) ? p1 : (lm == 2) ? p2 : p3;
            const float vB = (lm == 0) ? q0 : (lm == 1) ? q1 : (lm == 2) ? q2 : q3;
            const int eA = mb + quad * 4 + lm;
            const int eB = mb + 16 + quad * 4 + lm;
            if (eA < E) out[eA] = fmaxf(vA + b2s, 0.f);
            if (eB < E) out[eB] = fmaxf(vB + b2s, 0.f);
        }
    }
}

extern "C" void kernel_launch(void* const* d_in, const int* in_sizes, int n_in,
                              void* d_out, int out_size, void* d_ws, size_t ws_size,
                              hipStream_t stream)
{
    const float* x  = (const float*)d_in[0];
    const float* y  = (const float*)d_in[1];
    const int*   ei = (const int*)  d_in[2];
    const float* px = (const float*)d_in[3];
    const float* py = (const float*)d_in[4];
    const float* W1 = (const float*)d_in[5];
    const float* b1 = (const float*)d_in[6];
    const float* W2 = (const float*)d_in[7];
    const float* b2 = (const float*)d_in[8];
    float* out = (float*)d_out;
    const int E = in_sizes[2] / 2;
    const int nnode_elems = in_sizes[0];             // N_NODES * 64

    const size_t need = (size_t)nnode_elems * 2 * sizeof(short);
    if (ws_size >= need) {
        short* xb = (short*)d_ws;
        short* yb = xb + nnode_elems;
        cvt_kernel<<<dim3(1024), dim3(256), 0, stream>>>(x, y, xb, yb, nnode_elems);
        edge_mlp_kernel<true><<<dim3(768), dim3(256), 0, stream>>>(
            x, y, xb, yb, ei, px, py, W1, b1, W2, b2, out, E);
    } else {
        edge_mlp_kernel<false><<<dim3(768), dim3(256), 0, stream>>>(
            x, y, nullptr, nullptr, ei, px, py, W1, b1, W2, b2, out, E);
    }
}